// Round 3
// baseline (269.222 us; speedup 1.0000x reference)
//
#include <hip/hip_runtime.h>
#include <hip/hip_bf16.h>

typedef unsigned int u32;
typedef unsigned short u16;

#define DIM 128
#define LWS 136   // LDS row stride in u16 (128 + 8 pad = 272 B, 16B-aligned)

typedef __bf16 bfrag __attribute__((ext_vector_type(8)));   // MFMA A/B frag (4 VGPRs)
typedef float  facc  __attribute__((ext_vector_type(4)));   // MFMA C/D frag

__device__ __forceinline__ float2 bfpair(u32 u) {
    union { u32 i; float f; } lo, hi;
    lo.i = (u & 0xFFFFu) << 16;
    hi.i = u & 0xFFFF0000u;
    return make_float2(lo.f, hi.f);
}
__device__ __forceinline__ float bf1(u16 h) {
    union { u32 i; float f; } a; a.i = ((u32)h) << 16; return a.f;
}
__device__ __forceinline__ u16 f2bf(float f) {
    __hip_bfloat16 h = __float2bfloat16(f);   // RNE
    return *reinterpret_cast<u16*>(&h);
}
__device__ __forceinline__ u32 packbf(float x, float y) {
    return (u32)f2bf(x) | ((u32)f2bf(y) << 16);
}

template<bool BF16>
__device__ __forceinline__ float ldf(const void* p, int i) {
    if constexpr (BF16) return bf1(((const u16*)p)[i]);
    else                return ((const float*)p)[i];
}

// load an 8-element bf16 fragment from row-major [*,128] matrix (proven R2-R5)
template<bool BF16>
__device__ __forceinline__ bfrag ldfrag(const void* base, int row, int elt) {
    if constexpr (BF16) {
        const uint4* p = (const uint4*)((const u16*)base + (size_t)row * DIM + elt);
        return __builtin_bit_cast(bfrag, *p);
    } else {
        const float4* p = (const float4*)((const float*)base + (size_t)row * DIM + elt);
        float4 f0 = p[0], f1 = p[1];
        uint4 u = make_uint4(packbf(f0.x, f0.y), packbf(f0.z, f0.w),
                             packbf(f1.x, f1.y), packbf(f1.z, f1.w));
        return __builtin_bit_cast(bfrag, u);
    }
}

// ---------------------------------------------------------------------------
// Sniffer (R2-proven): flags[0]=1 if float tensors are bf16; flags[1]=1 if
// edge_index is int64 layout.
// ---------------------------------------------------------------------------
__global__ __launch_bounds__(64) void sniff_kernel(const u32* __restrict__ x0w,
                                                   const int* __restrict__ eiw,
                                                   int* __restrict__ flags) {
    int l = threadIdx.x;
    u32 w = x0w[l];
    u32 ef = (w >> 7) & 0xFF;                 // exponent of low halfword if bf16
    bool inr = (ef >= 99 && ef <= 141);
    unsigned long long m1 = __ballot(inr);
    bool zodd = (eiw[2 * l + 1] == 0);
    unsigned long long m2 = __ballot(zodd);
    if (l == 0) {
        flags[0] = (__popcll(m1) >= 48) ? 1 : 0;
        flags[1] = (__popcll(m2) >= 32) ? 1 : 0;
    }
}

// ---------------------------------------------------------------------------
// MFMA projection, R4-submission-proven math (A=x, B=W, proven C-layout &
// epilogue) + LDS-staged W (converted to bf16 at staging time; bit-identical
// values to the proven ldfrag path). One block = one matrix (grp), 4 chunks.
// ---------------------------------------------------------------------------
template<bool BF16>
__global__ __launch_bounds__(256) void proj_kernel(
    const void* __restrict__ x0v,
    const void* __restrict__ W1v, const void* __restrict__ b1v,
    const void* __restrict__ W2v, const void* __restrict__ b2v,
    const void* __restrict__ a1wv, const void* __restrict__ a1bv,
    const void* __restrict__ a2wv, const void* __restrict__ a2bv,
    u16* __restrict__ xj, float* __restrict__ a1, float* __restrict__ a2,
    const int* __restrict__ flags, int n, int nchunk, int bpg)
{
    if ((flags[0] != 0) != BF16) return;      // wrong dtype: ghost launch
    __shared__ u16 lw[128 * LWS];             // ~34 KB

    const int t   = threadIdx.x;
    const int grp = blockIdx.x / bpg;         // 0: W1/a1, 1: W2/a2
    const int cb  = blockIdx.x % bpg;

    const void* Wv  = grp ? W2v  : W1v;
    const void* bv  = grp ? b2v  : b1v;
    const void* awv = grp ? a2wv : a1wv;
    const void* abv = grp ? a2bv : a1bv;
    float* aout     = grp ? a2   : a1;

    // stage W -> LDS as bf16 (16B chunks, padded rows)
    for (int j = t; j < 2048; j += 256) {
        int r = j >> 4, c = j & 15;
        uint4 u;
        if constexpr (BF16) {
            u = *(const uint4*)((const u16*)Wv + (size_t)r * DIM + c * 8);
        } else {
            const float4* p = (const float4*)((const float*)Wv + (size_t)r * DIM + c * 8);
            float4 f0 = p[0], f1 = p[1];
            u = make_uint4(packbf(f0.x, f0.y), packbf(f0.z, f0.w),
                           packbf(f1.x, f1.y), packbf(f1.z, f1.w));
        }
        *(uint4*)(lw + (size_t)r * LWS + c * 8) = u;
    }
    __syncthreads();

    const int wid = t >> 6, l = t & 63;
    const int chunk = cb * 4 + wid;
    if (chunk >= nchunk) return;
    const int r0 = chunk * 32;
    const int lr = l & 15;                    // A row / B col within tile
    const int q  = l >> 4;                    // quad -> k slice, C row group

    // A fragments = x rows: 2 row-tiles x 4 k-slices (proven)
    bfrag a[2][4];
    #pragma unroll
    for (int rt = 0; rt < 2; ++rt) {
        int row = min(r0 + rt * 16 + lr, n - 1);  // clamp (stores guarded)
        #pragma unroll
        for (int k = 0; k < 4; ++k)
            a[rt][k] = ldfrag<BF16>(x0v, row, k * 32 + q * 8);
    }

    facc acc[2][8];
    #pragma unroll
    for (int rt = 0; rt < 2; ++rt)
        #pragma unroll
        for (int ct = 0; ct < 8; ++ct)
            acc[rt][ct] = (facc){0.f, 0.f, 0.f, 0.f};

    #pragma unroll
    for (int ct = 0; ct < 8; ++ct) {
        bfrag b[4];
        const u16* lrow = lw + (size_t)(ct * 16 + lr) * LWS;
        #pragma unroll
        for (int k = 0; k < 4; ++k)
            b[k] = *(const bfrag*)(lrow + k * 32 + q * 8);
        #pragma unroll
        for (int rt = 0; rt < 2; ++rt)
            #pragma unroll
            for (int k = 0; k < 4; ++k)
                acc[rt][ct] = __builtin_amdgcn_mfma_f32_16x16x32_bf16(
                    a[rt][k], b[k], acc[rt][ct], 0, 0, 0);
    }

    // proven epilogue: bias + LeakyReLU; scalar xj stores; a-dot
    float s[2][4] = {{0.f,0.f,0.f,0.f},{0.f,0.f,0.f,0.f}};
    #pragma unroll
    for (int ct = 0; ct < 8; ++ct) {
        float bc  = ldf<BF16>(bv,  ct * 16 + lr);
        float awc = ldf<BF16>(awv, ct * 16 + lr);
        #pragma unroll
        for (int rt = 0; rt < 2; ++rt)
            #pragma unroll
            for (int reg = 0; reg < 4; ++reg) {
                float v = acc[rt][ct][reg] + bc;
                v = v >= 0.f ? v : 0.2f * v;          // LeakyReLU(0.2)
                int row = r0 + rt * 16 + q * 4 + reg;
                if (grp && row < n)
                    xj[(size_t)row * DIM + ct * 16 + lr] = f2bf(v);
                s[rt][reg] = fmaf(v, awc, s[rt][reg]);
            }
    }
    #pragma unroll
    for (int off = 1; off < 16; off <<= 1)
        #pragma unroll
        for (int rt = 0; rt < 2; ++rt)
            #pragma unroll
            for (int reg = 0; reg < 4; ++reg)
                s[rt][reg] += __shfl_xor(s[rt][reg], off);
    if (lr == 0) {
        float ab = ldf<BF16>(abv, 0);
        #pragma unroll
        for (int rt = 0; rt < 2; ++rt)
            #pragma unroll
            for (int reg = 0; reg < 4; ++reg) {
                int row = r0 + rt * 16 + q * 4 + reg;
                if (row < n) aout[row] = s[rt][reg] + ab;
            }
    }
}

// ---------------------------------------------------------------------------
// CSR step 1: degree histogram over src.
// R7: 4 edges/thread, vectorized ei loads (int64 layout packs 2 edges/16B),
// 4 independent atomics in flight (same MLP medicine as R6 gather).
// ---------------------------------------------------------------------------
__global__ __launch_bounds__(256) void hist_kernel(
    const int* __restrict__ ei, int* __restrict__ deg,
    const int* __restrict__ flags, int ne)
{
    int i0 = (blockIdx.x * 256 + threadIdx.x) * 4;
    if (i0 >= ne) return;
    const bool i64 = flags[1] != 0;
    if (i0 + 4 <= ne && (ne & 3) == 0) {
        int src[4];
        if (i64) {
            int4 s0 = *(const int4*)(ei + 2 * i0);
            int4 s1 = *(const int4*)(ei + 2 * i0 + 4);
            src[0] = s0.x; src[1] = s0.z; src[2] = s1.x; src[3] = s1.z;
        } else {
            int4 s = *(const int4*)(ei + i0);
            src[0] = s.x; src[1] = s.y; src[2] = s.z; src[3] = s.w;
        }
        #pragma unroll
        for (int j = 0; j < 4; ++j) atomicAdd(&deg[src[j]], 1);
    } else {
        for (int i = i0; i < ne && i < i0 + 4; ++i) {
            int src = i64 ? ei[2 * i] : ei[i];
            atomicAdd(&deg[src], 1);
        }
    }
}

// ---------------------------------------------------------------------------
// Parallel scan (3 phases, proven).
// ---------------------------------------------------------------------------
__global__ __launch_bounds__(256) void scanA_kernel(
    const int* __restrict__ deg, int* __restrict__ ptr,
    int* __restrict__ bsum, int n)
{
    __shared__ int wsums[4];
    const int t = threadIdx.x, lane = t & 63, w = t >> 6;
    const int i = blockIdx.x * 1024 + t * 4;

    int4 d = make_int4(0, 0, 0, 0);
    if (i < n) d = *(const int4*)(deg + i);      // n % 4 == 0
    int ts = d.x + d.y + d.z + d.w;
    int sc = ts;
    #pragma unroll
    for (int off = 1; off < 64; off <<= 1) {
        int v = __shfl_up(sc, off);
        if (lane >= off) sc += v;
    }
    if (lane == 63) wsums[w] = sc;
    __syncthreads();
    int wb = 0;
    #pragma unroll
    for (int j = 0; j < 4; ++j) if (j < w) wb += wsums[j];
    int excl = wb + sc - ts;
    if (i < n) {
        int4 o;
        o.x = excl; o.y = o.x + d.x; o.z = o.y + d.y; o.w = o.z + d.z;
        *(int4*)(ptr + i) = o;
    }
    if (t == 0) bsum[blockIdx.x] = wsums[0] + wsums[1] + wsums[2] + wsums[3];
}

__global__ __launch_bounds__(64) void scanB_kernel(
    int* __restrict__ bsum, int* __restrict__ ptr, int nblk, int n)
{
    int l = threadIdx.x;
    int v = (l < nblk) ? bsum[l] : 0;
    int s = v;
    #pragma unroll
    for (int off = 1; off < 64; off <<= 1) {
        int u = __shfl_up(s, off);
        if (l >= off) s += u;
    }
    if (l < nblk) bsum[l] = s - v;               // exclusive offsets
    if (l == 63) ptr[n] = s;                     // grand total == ne
}

__global__ __launch_bounds__(256) void scanC_kernel(
    int* __restrict__ ptr, int* __restrict__ cursor,
    const int* __restrict__ bsum, int n)
{
    const int i = blockIdx.x * 1024 + threadIdx.x * 4;
    if (i >= n) return;
    int off = bsum[blockIdx.x];
    int4 v = *(const int4*)(ptr + i);
    v.x += off; v.y += off; v.z += off; v.w += off;
    *(int4*)(ptr + i) = v;
    *(int4*)(cursor + i) = v;
}

// ---------------------------------------------------------------------------
// CSR step 3: scatter {dst, att} into src-sorted order.
// R7: 4 edges/thread. The old kernel was latency-bound at MLP=1 (VALUBusy
// 1.2%, hbm 15%): per-edge dependent chain ei-load -> a1/a2 gathers ->
// atomicAdd round trip -> store. Batching 4 edges overlaps 4 chains:
// vector ei loads, 4 independent gathers, 4 independent atomics, 4 stores.
// Math per edge identical (f32 sigmoid); segment order remains arbitrary
// (segment_sum is order-independent within tolerance, already accepted).
// ---------------------------------------------------------------------------
__global__ __launch_bounds__(256) void scatter_kernel(
    const int* __restrict__ ei, const float* __restrict__ a1,
    const float* __restrict__ a2, int* __restrict__ cursor,
    uint2* __restrict__ sorted, const int* __restrict__ flags, int ne)
{
    int i0 = (blockIdx.x * 256 + threadIdx.x) * 4;
    if (i0 >= ne) return;
    const bool i64 = flags[1] != 0;

    if (i0 + 4 <= ne && (ne & 3) == 0) {
        int src[4], dst[4];
        if (i64) {
            int4 s0 = *(const int4*)(ei + 2 * i0);
            int4 s1 = *(const int4*)(ei + 2 * i0 + 4);
            int4 d0 = *(const int4*)(ei + 2 * (ne + i0));
            int4 d1 = *(const int4*)(ei + 2 * (ne + i0) + 4);
            src[0] = s0.x; src[1] = s0.z; src[2] = s1.x; src[3] = s1.z;
            dst[0] = d0.x; dst[1] = d0.z; dst[2] = d1.x; dst[3] = d1.z;
        } else {
            int4 s = *(const int4*)(ei + i0);
            int4 d = *(const int4*)(ei + ne + i0);
            src[0] = s.x; src[1] = s.y; src[2] = s.z; src[3] = s.w;
            dst[0] = d.x; dst[1] = d.y; dst[2] = d.z; dst[3] = d.w;
        }
        // 4 independent a1/a2 gathers (compiler issues all 8 loads, one wait)
        float v1[4], v2[4];
        #pragma unroll
        for (int j = 0; j < 4; ++j) v1[j] = a1[src[j]];
        #pragma unroll
        for (int j = 0; j < 4; ++j) v2[j] = a2[dst[j]];
        // 4 independent atomics in flight
        int pos[4];
        #pragma unroll
        for (int j = 0; j < 4; ++j) pos[j] = atomicAdd(&cursor[src[j]], 1);
        #pragma unroll
        for (int j = 0; j < 4; ++j) {
            float av  = v1[j] + v2[j];
            float att = 1.0f / (1.0f + __expf(-av));
            uint2 rec; rec.x = (u32)dst[j]; rec.y = __float_as_uint(att);
            sorted[pos[j]] = rec;
        }
    } else {
        for (int i = i0; i < ne && i < i0 + 4; ++i) {
            int src, dst;
            if (i64) { src = ei[2 * i]; dst = ei[2 * (ne + i)]; }
            else     { src = ei[i];     dst = ei[ne + i];       }
            float av  = a1[src] + a2[dst];
            float att = 1.0f / (1.0f + __expf(-av));
            int pos = atomicAdd(&cursor[src], 1);
            uint2 rec; rec.x = (u32)dst; rec.y = __float_as_uint(att);
            sorted[pos] = rec;
        }
    }
}

// ---------------------------------------------------------------------------
// Gather (R6-proven): one wave per src node, lane l = cols 2l,2l+1.
// Depth-8 software pipeline: 8 independent xj row loads in flight; dual
// accumulators break the FMA chain. 59.6us -> sub-48us measured.
// ---------------------------------------------------------------------------
template<bool BF16>
__global__ __launch_bounds__(256) void gather_kernel(
    const int* __restrict__ ptr, const uint2* __restrict__ sorted,
    const u32* __restrict__ xjw, const void* __restrict__ x0v,
    void* __restrict__ outv, const int* __restrict__ flags, int n)
{
    if ((flags[0] != 0) != BF16) return;
    int s = blockIdx.x * 4 + (threadIdx.x >> 6);
    int l = threadIdx.x & 63;
    if (s >= n) return;

    float2 acc0, acc1;
    if constexpr (BF16) acc0 = bfpair(((const u32*)x0v)[(size_t)s * 64 + l]);
    else                acc0 = ((const float2*)x0v)[(size_t)s * 64 + l];
    acc1 = make_float2(0.f, 0.f);

    int k = ptr[s], end = ptr[s + 1];

    // main chunks: 8 edges in flight
    while (k + 8 <= end) {
        uint2 r[8];
        #pragma unroll
        for (int j = 0; j < 8; ++j) r[j] = sorted[k + j];
        u32 w[8];
        #pragma unroll
        for (int j = 0; j < 8; ++j) w[j] = xjw[(size_t)r[j].x * 64 + l];
        #pragma unroll
        for (int j = 0; j < 8; ++j) {
            float att = __uint_as_float(r[j].y);
            float2 xv = bfpair(w[j]);
            if (j & 1) { acc1.x = fmaf(att, xv.x, acc1.x);
                         acc1.y = fmaf(att, xv.y, acc1.y); }
            else       { acc0.x = fmaf(att, xv.x, acc0.x);
                         acc0.y = fmaf(att, xv.y, acc0.y); }
        }
        k += 8;
    }
    // one chunk of 4
    if (k + 4 <= end) {
        uint2 r[4];
        #pragma unroll
        for (int j = 0; j < 4; ++j) r[j] = sorted[k + j];
        u32 w[4];
        #pragma unroll
        for (int j = 0; j < 4; ++j) w[j] = xjw[(size_t)r[j].x * 64 + l];
        #pragma unroll
        for (int j = 0; j < 4; ++j) {
            float att = __uint_as_float(r[j].y);
            float2 xv = bfpair(w[j]);
            if (j & 1) { acc1.x = fmaf(att, xv.x, acc1.x);
                         acc1.y = fmaf(att, xv.y, acc1.y); }
            else       { acc0.x = fmaf(att, xv.x, acc0.x);
                         acc0.y = fmaf(att, xv.y, acc0.y); }
        }
        k += 4;
    }
    // scalar tail (<=3)
    for (; k < end; ++k) {
        uint2 cur = sorted[k];
        float att = __uint_as_float(cur.y);
        float2 xv = bfpair(xjw[(size_t)cur.x * 64 + l]);
        acc0.x = fmaf(att, xv.x, acc0.x);
        acc0.y = fmaf(att, xv.y, acc0.y);
    }
    acc0.x += acc1.x;
    acc0.y += acc1.y;

    if constexpr (BF16) ((u32*)outv)[(size_t)s * 64 + l] = packbf(acc0.x, acc0.y);
    else                ((float2*)outv)[(size_t)s * 64 + l] = acc0;
}

extern "C" void kernel_launch(void* const* d_in, const int* in_sizes, int n_in,
                              void* d_out, int out_size, void* d_ws, size_t ws_size,
                              hipStream_t stream)
{
    const void* x0  = d_in[0];
    /* d_in[1] = x1: unused by the reference computation */
    const int*  ei  = (const int*)d_in[2];
    const void* W1  = d_in[3];
    const void* b1  = d_in[4];
    const void* W2  = d_in[5];
    const void* b2  = d_in[6];
    const void* a1w = d_in[7];
    const void* a1b = d_in[8];
    const void* a2w = d_in[9];
    const void* a2b = d_in[10];

    const int n = in_sizes[0] / DIM;        // 50000
    const int e = in_sizes[2] / 2;          // 800000

    // ws: flags | bsum | xj bf16 | a1 | a2 | deg | ptr | cursor | sorted(uint2)
    char* ws = (char*)d_ws;
    int* flags = (int*)ws;
    int* bsum  = (int*)(ws + 256);          // up to 192 block sums
    size_t off = 1024;
    u16* xj = (u16*)(ws + off);
    off += (size_t)n * DIM * sizeof(u16);   off = (off + 255) & ~(size_t)255;
    float* a1 = (float*)(ws + off);
    off += (size_t)n * sizeof(float);       off = (off + 255) & ~(size_t)255;
    float* a2 = (float*)(ws + off);
    off += (size_t)n * sizeof(float);       off = (off + 255) & ~(size_t)255;
    int* deg = (int*)(ws + off);
    off += (size_t)n * sizeof(int);         off = (off + 255) & ~(size_t)255;
    int* ptr = (int*)(ws + off);
    off += (size_t)(n + 1) * sizeof(int);   off = (off + 255) & ~(size_t)255;
    int* cursor = (int*)(ws + off);
    off += (size_t)n * sizeof(int);         off = (off + 255) & ~(size_t)255;
    uint2* sorted = (uint2*)(ws + off);

    hipMemsetAsync(deg, 0, (size_t)n * sizeof(int), stream);
    sniff_kernel<<<1, 64, 0, stream>>>((const u32*)x0, ei, flags);

    const int nchunk = (n + 31) / 32;       // 1563
    const int bpg = (nchunk + 3) / 4;       // blocks per matrix
    proj_kernel<true ><<<2 * bpg, 256, 0, stream>>>(x0, W1, b1, W2, b2, a1w, a1b,
                                                    a2w, a2b, xj, a1, a2, flags, n, nchunk, bpg);
    proj_kernel<false><<<2 * bpg, 256, 0, stream>>>(x0, W1, b1, W2, b2, a1w, a1b,
                                                    a2w, a2b, xj, a1, a2, flags, n, nchunk, bpg);

    int eblocks4 = (e + 1023) / 1024;       // 4 edges per thread
    hist_kernel<<<eblocks4, 256, 0, stream>>>(ei, deg, flags, e);
    int sblocks = (n + 1023) / 1024;
    scanA_kernel<<<sblocks, 256, 0, stream>>>(deg, ptr, bsum, n);
    scanB_kernel<<<1, 64, 0, stream>>>(bsum, ptr, sblocks, n);
    scanC_kernel<<<sblocks, 256, 0, stream>>>(ptr, cursor, bsum, n);
    scatter_kernel<<<eblocks4, 256, 0, stream>>>(ei, a1, a2, cursor, sorted, flags, e);

    int gblocks = (n + 3) / 4;
    gather_kernel<true ><<<gblocks, 256, 0, stream>>>(ptr, sorted, (const u32*)xj,
                                                      x0, d_out, flags, n);
    gather_kernel<false><<<gblocks, 256, 0, stream>>>(ptr, sorted, (const u32*)xj,
                                                      x0, d_out, flags, n);
}

// Round 4
// 229.978 us; speedup vs baseline: 1.1706x; 1.1706x over previous
//
#include <hip/hip_runtime.h>
#include <hip/hip_bf16.h>

typedef unsigned int u32;
typedef unsigned short u16;

#define DIM 128
#define LWS 136   // LDS row stride in u16 (128 + 8 pad = 272 B, 16B-aligned)

typedef __bf16 bfrag __attribute__((ext_vector_type(8)));   // MFMA A/B frag (4 VGPRs)
typedef float  facc  __attribute__((ext_vector_type(4)));   // MFMA C/D frag

__device__ __forceinline__ float2 bfpair(u32 u) {
    union { u32 i; float f; } lo, hi;
    lo.i = (u & 0xFFFFu) << 16;
    hi.i = u & 0xFFFF0000u;
    return make_float2(lo.f, hi.f);
}
__device__ __forceinline__ float bf1(u16 h) {
    union { u32 i; float f; } a; a.i = ((u32)h) << 16; return a.f;
}
__device__ __forceinline__ u16 f2bf(float f) {
    __hip_bfloat16 h = __float2bfloat16(f);   // RNE
    return *reinterpret_cast<u16*>(&h);
}
__device__ __forceinline__ u32 packbf(float x, float y) {
    return (u32)f2bf(x) | ((u32)f2bf(y) << 16);
}

template<bool BF16>
__device__ __forceinline__ float ldf(const void* p, int i) {
    if constexpr (BF16) return bf1(((const u16*)p)[i]);
    else                return ((const float*)p)[i];
}

// load an 8-element bf16 fragment from row-major [*,128] matrix (proven R2-R5)
template<bool BF16>
__device__ __forceinline__ bfrag ldfrag(const void* base, int row, int elt) {
    if constexpr (BF16) {
        const uint4* p = (const uint4*)((const u16*)base + (size_t)row * DIM + elt);
        return __builtin_bit_cast(bfrag, *p);
    } else {
        const float4* p = (const float4*)((const float*)base + (size_t)row * DIM + elt);
        float4 f0 = p[0], f1 = p[1];
        uint4 u = make_uint4(packbf(f0.x, f0.y), packbf(f0.z, f0.w),
                             packbf(f1.x, f1.y), packbf(f1.z, f1.w));
        return __builtin_bit_cast(bfrag, u);
    }
}

// ---------------------------------------------------------------------------
// Sniffer (R2-proven): flags[0]=1 if float tensors are bf16; flags[1]=1 if
// edge_index is int64 layout.
// ---------------------------------------------------------------------------
__global__ __launch_bounds__(64) void sniff_kernel(const u32* __restrict__ x0w,
                                                   const int* __restrict__ eiw,
                                                   int* __restrict__ flags) {
    int l = threadIdx.x;
    u32 w = x0w[l];
    u32 ef = (w >> 7) & 0xFF;                 // exponent of low halfword if bf16
    bool inr = (ef >= 99 && ef <= 141);
    unsigned long long m1 = __ballot(inr);
    bool zodd = (eiw[2 * l + 1] == 0);
    unsigned long long m2 = __ballot(zodd);
    if (l == 0) {
        flags[0] = (__popcll(m1) >= 48) ? 1 : 0;
        flags[1] = (__popcll(m2) >= 32) ? 1 : 0;
    }
}

// ---------------------------------------------------------------------------
// MFMA projection, R4-submission-proven math (A=x, B=W, proven C-layout &
// epilogue) + LDS-staged W (converted to bf16 at staging time; bit-identical
// values to the proven ldfrag path). One block = one matrix (grp), 4 chunks.
// ---------------------------------------------------------------------------
template<bool BF16>
__global__ __launch_bounds__(256) void proj_kernel(
    const void* __restrict__ x0v,
    const void* __restrict__ W1v, const void* __restrict__ b1v,
    const void* __restrict__ W2v, const void* __restrict__ b2v,
    const void* __restrict__ a1wv, const void* __restrict__ a1bv,
    const void* __restrict__ a2wv, const void* __restrict__ a2bv,
    u16* __restrict__ xj, float* __restrict__ a1, float* __restrict__ a2,
    const int* __restrict__ flags, int n, int nchunk, int bpg)
{
    if ((flags[0] != 0) != BF16) return;      // wrong dtype: ghost launch
    __shared__ u16 lw[128 * LWS];             // ~34 KB

    const int t   = threadIdx.x;
    const int grp = blockIdx.x / bpg;         // 0: W1/a1, 1: W2/a2
    const int cb  = blockIdx.x % bpg;

    const void* Wv  = grp ? W2v  : W1v;
    const void* bv  = grp ? b2v  : b1v;
    const void* awv = grp ? a2wv : a1wv;
    const void* abv = grp ? a2bv : a1bv;
    float* aout     = grp ? a2   : a1;

    // stage W -> LDS as bf16 (16B chunks, padded rows)
    for (int j = t; j < 2048; j += 256) {
        int r = j >> 4, c = j & 15;
        uint4 u;
        if constexpr (BF16) {
            u = *(const uint4*)((const u16*)Wv + (size_t)r * DIM + c * 8);
        } else {
            const float4* p = (const float4*)((const float*)Wv + (size_t)r * DIM + c * 8);
            float4 f0 = p[0], f1 = p[1];
            u = make_uint4(packbf(f0.x, f0.y), packbf(f0.z, f0.w),
                           packbf(f1.x, f1.y), packbf(f1.z, f1.w));
        }
        *(uint4*)(lw + (size_t)r * LWS + c * 8) = u;
    }
    __syncthreads();

    const int wid = t >> 6, l = t & 63;
    const int chunk = cb * 4 + wid;
    if (chunk >= nchunk) return;
    const int r0 = chunk * 32;
    const int lr = l & 15;                    // A row / B col within tile
    const int q  = l >> 4;                    // quad -> k slice, C row group

    // A fragments = x rows: 2 row-tiles x 4 k-slices (proven)
    bfrag a[2][4];
    #pragma unroll
    for (int rt = 0; rt < 2; ++rt) {
        int row = min(r0 + rt * 16 + lr, n - 1);  // clamp (stores guarded)
        #pragma unroll
        for (int k = 0; k < 4; ++k)
            a[rt][k] = ldfrag<BF16>(x0v, row, k * 32 + q * 8);
    }

    facc acc[2][8];
    #pragma unroll
    for (int rt = 0; rt < 2; ++rt)
        #pragma unroll
        for (int ct = 0; ct < 8; ++ct)
            acc[rt][ct] = (facc){0.f, 0.f, 0.f, 0.f};

    #pragma unroll
    for (int ct = 0; ct < 8; ++ct) {
        bfrag b[4];
        const u16* lrow = lw + (size_t)(ct * 16 + lr) * LWS;
        #pragma unroll
        for (int k = 0; k < 4; ++k)
            b[k] = *(const bfrag*)(lrow + k * 32 + q * 8);
        #pragma unroll
        for (int rt = 0; rt < 2; ++rt)
            #pragma unroll
            for (int k = 0; k < 4; ++k)
                acc[rt][ct] = __builtin_amdgcn_mfma_f32_16x16x32_bf16(
                    a[rt][k], b[k], acc[rt][ct], 0, 0, 0);
    }

    // proven epilogue: bias + LeakyReLU; scalar xj stores; a-dot
    float s[2][4] = {{0.f,0.f,0.f,0.f},{0.f,0.f,0.f,0.f}};
    #pragma unroll
    for (int ct = 0; ct < 8; ++ct) {
        float bc  = ldf<BF16>(bv,  ct * 16 + lr);
        float awc = ldf<BF16>(awv, ct * 16 + lr);
        #pragma unroll
        for (int rt = 0; rt < 2; ++rt)
            #pragma unroll
            for (int reg = 0; reg < 4; ++reg) {
                float v = acc[rt][ct][reg] + bc;
                v = v >= 0.f ? v : 0.2f * v;          // LeakyReLU(0.2)
                int row = r0 + rt * 16 + q * 4 + reg;
                if (grp && row < n)
                    xj[(size_t)row * DIM + ct * 16 + lr] = f2bf(v);
                s[rt][reg] = fmaf(v, awc, s[rt][reg]);
            }
    }
    #pragma unroll
    for (int off = 1; off < 16; off <<= 1)
        #pragma unroll
        for (int rt = 0; rt < 2; ++rt)
            #pragma unroll
            for (int reg = 0; reg < 4; ++reg)
                s[rt][reg] += __shfl_xor(s[rt][reg], off);
    if (lr == 0) {
        float ab = ldf<BF16>(abv, 0);
        #pragma unroll
        for (int rt = 0; rt < 2; ++rt)
            #pragma unroll
            for (int reg = 0; reg < 4; ++reg) {
                int row = r0 + rt * 16 + q * 4 + reg;
                if (row < n) aout[row] = s[rt][reg] + ab;
            }
    }
}

// ---------------------------------------------------------------------------
// CSR step 1: degree histogram over src (R6 shape: 1 edge/thread, max TLP —
// R7 showed 4 edges/thread starves the grid of waves and regresses).
// R8: persist the atomicAdd return as the edge's rank within its segment
// (coalesced 4B store). pos = ptr[src] + rank later, so scatter needs no
// atomic round-trip.
// ---------------------------------------------------------------------------
__global__ __launch_bounds__(256) void hist_kernel(
    const int* __restrict__ ei, int* __restrict__ deg,
    int* __restrict__ rank, const int* __restrict__ flags, int ne)
{
    int i = blockIdx.x * 256 + threadIdx.x;
    if (i >= ne) return;
    int src = flags[1] ? ei[2 * i] : ei[i];
    rank[i] = atomicAdd(&deg[src], 1);
}

// ---------------------------------------------------------------------------
// Parallel scan (3 phases, proven).
// ---------------------------------------------------------------------------
__global__ __launch_bounds__(256) void scanA_kernel(
    const int* __restrict__ deg, int* __restrict__ ptr,
    int* __restrict__ bsum, int n)
{
    __shared__ int wsums[4];
    const int t = threadIdx.x, lane = t & 63, w = t >> 6;
    const int i = blockIdx.x * 1024 + t * 4;

    int4 d = make_int4(0, 0, 0, 0);
    if (i < n) d = *(const int4*)(deg + i);      // n % 4 == 0
    int ts = d.x + d.y + d.z + d.w;
    int sc = ts;
    #pragma unroll
    for (int off = 1; off < 64; off <<= 1) {
        int v = __shfl_up(sc, off);
        if (lane >= off) sc += v;
    }
    if (lane == 63) wsums[w] = sc;
    __syncthreads();
    int wb = 0;
    #pragma unroll
    for (int j = 0; j < 4; ++j) if (j < w) wb += wsums[j];
    int excl = wb + sc - ts;
    if (i < n) {
        int4 o;
        o.x = excl; o.y = o.x + d.x; o.z = o.y + d.y; o.w = o.z + d.z;
        *(int4*)(ptr + i) = o;
    }
    if (t == 0) bsum[blockIdx.x] = wsums[0] + wsums[1] + wsums[2] + wsums[3];
}

__global__ __launch_bounds__(64) void scanB_kernel(
    int* __restrict__ bsum, int* __restrict__ ptr, int nblk, int n)
{
    int l = threadIdx.x;
    int v = (l < nblk) ? bsum[l] : 0;
    int s = v;
    #pragma unroll
    for (int off = 1; off < 64; off <<= 1) {
        int u = __shfl_up(s, off);
        if (l >= off) s += u;
    }
    if (l < nblk) bsum[l] = s - v;               // exclusive offsets
    if (l == 63) ptr[n] = s;                     // grand total == ne
}

__global__ __launch_bounds__(256) void scanC_kernel(
    int* __restrict__ ptr, const int* __restrict__ bsum, int n)
{
    const int i = blockIdx.x * 1024 + threadIdx.x * 4;
    if (i >= n) return;
    int off = bsum[blockIdx.x];
    int4 v = *(const int4*)(ptr + i);
    v.x += off; v.y += off; v.z += off; v.w += off;
    *(int4*)(ptr + i) = v;
}

// ---------------------------------------------------------------------------
// CSR step 3: scatter {dst, att} into src-sorted order.
// R8: atomic-free. pos = ptr[src] + rank[i] (rank persisted by hist).
// 1 edge/thread (R6-proven TLP). Chain is now ei -> {ptr, a1, a2 gathers,
// rank} all independent -> store. All gathered arrays (ptr 200KB, a1/a2
// 200KB each) are L2-resident. Random 8B stores (the 64B-line write
// amplification, WRITE_SIZE ~53MB) unchanged this round.
// ---------------------------------------------------------------------------
__global__ __launch_bounds__(256) void scatter_kernel(
    const int* __restrict__ ei, const float* __restrict__ a1,
    const float* __restrict__ a2, const int* __restrict__ ptr,
    const int* __restrict__ rank, uint2* __restrict__ sorted,
    const int* __restrict__ flags, int ne)
{
    int i = blockIdx.x * 256 + threadIdx.x;
    if (i >= ne) return;
    int src, dst;
    if (flags[1]) { src = ei[2 * i]; dst = ei[2 * (ne + i)]; }
    else          { src = ei[i];     dst = ei[ne + i];       }
    int  r   = rank[i];
    int  pb  = ptr[src];
    float av  = a1[src] + a2[dst];
    float att = 1.0f / (1.0f + __expf(-av));
    uint2 rec; rec.x = (u32)dst; rec.y = __float_as_uint(att);
    sorted[pb + r] = rec;
}

// ---------------------------------------------------------------------------
// Gather (R6-proven): one wave per src node, lane l = cols 2l,2l+1.
// Depth-8 software pipeline: 8 independent xj row loads in flight; dual
// accumulators break the FMA chain. 59.6us -> sub-48us measured.
// ---------------------------------------------------------------------------
template<bool BF16>
__global__ __launch_bounds__(256) void gather_kernel(
    const int* __restrict__ ptr, const uint2* __restrict__ sorted,
    const u32* __restrict__ xjw, const void* __restrict__ x0v,
    void* __restrict__ outv, const int* __restrict__ flags, int n)
{
    if ((flags[0] != 0) != BF16) return;
    int s = blockIdx.x * 4 + (threadIdx.x >> 6);
    int l = threadIdx.x & 63;
    if (s >= n) return;

    float2 acc0, acc1;
    if constexpr (BF16) acc0 = bfpair(((const u32*)x0v)[(size_t)s * 64 + l]);
    else                acc0 = ((const float2*)x0v)[(size_t)s * 64 + l];
    acc1 = make_float2(0.f, 0.f);

    int k = ptr[s], end = ptr[s + 1];

    // main chunks: 8 edges in flight
    while (k + 8 <= end) {
        uint2 r[8];
        #pragma unroll
        for (int j = 0; j < 8; ++j) r[j] = sorted[k + j];
        u32 w[8];
        #pragma unroll
        for (int j = 0; j < 8; ++j) w[j] = xjw[(size_t)r[j].x * 64 + l];
        #pragma unroll
        for (int j = 0; j < 8; ++j) {
            float att = __uint_as_float(r[j].y);
            float2 xv = bfpair(w[j]);
            if (j & 1) { acc1.x = fmaf(att, xv.x, acc1.x);
                         acc1.y = fmaf(att, xv.y, acc1.y); }
            else       { acc0.x = fmaf(att, xv.x, acc0.x);
                         acc0.y = fmaf(att, xv.y, acc0.y); }
        }
        k += 8;
    }
    // one chunk of 4
    if (k + 4 <= end) {
        uint2 r[4];
        #pragma unroll
        for (int j = 0; j < 4; ++j) r[j] = sorted[k + j];
        u32 w[4];
        #pragma unroll
        for (int j = 0; j < 4; ++j) w[j] = xjw[(size_t)r[j].x * 64 + l];
        #pragma unroll
        for (int j = 0; j < 4; ++j) {
            float att = __uint_as_float(r[j].y);
            float2 xv = bfpair(w[j]);
            if (j & 1) { acc1.x = fmaf(att, xv.x, acc1.x);
                         acc1.y = fmaf(att, xv.y, acc1.y); }
            else       { acc0.x = fmaf(att, xv.x, acc0.x);
                         acc0.y = fmaf(att, xv.y, acc0.y); }
        }
        k += 4;
    }
    // scalar tail (<=3)
    for (; k < end; ++k) {
        uint2 cur = sorted[k];
        float att = __uint_as_float(cur.y);
        float2 xv = bfpair(xjw[(size_t)cur.x * 64 + l]);
        acc0.x = fmaf(att, xv.x, acc0.x);
        acc0.y = fmaf(att, xv.y, acc0.y);
    }
    acc0.x += acc1.x;
    acc0.y += acc1.y;

    if constexpr (BF16) ((u32*)outv)[(size_t)s * 64 + l] = packbf(acc0.x, acc0.y);
    else                ((float2*)outv)[(size_t)s * 64 + l] = acc0;
}

extern "C" void kernel_launch(void* const* d_in, const int* in_sizes, int n_in,
                              void* d_out, int out_size, void* d_ws, size_t ws_size,
                              hipStream_t stream)
{
    const void* x0  = d_in[0];
    /* d_in[1] = x1: unused by the reference computation */
    const int*  ei  = (const int*)d_in[2];
    const void* W1  = d_in[3];
    const void* b1  = d_in[4];
    const void* W2  = d_in[5];
    const void* b2  = d_in[6];
    const void* a1w = d_in[7];
    const void* a1b = d_in[8];
    const void* a2w = d_in[9];
    const void* a2b = d_in[10];

    const int n = in_sizes[0] / DIM;        // 50000
    const int e = in_sizes[2] / 2;          // 800000

    // ws: flags | bsum | xj bf16 | a1 | a2 | deg | ptr | rank | sorted(uint2)
    char* ws = (char*)d_ws;
    int* flags = (int*)ws;
    int* bsum  = (int*)(ws + 256);          // up to 192 block sums
    size_t off = 1024;
    u16* xj = (u16*)(ws + off);
    off += (size_t)n * DIM * sizeof(u16);   off = (off + 255) & ~(size_t)255;
    float* a1 = (float*)(ws + off);
    off += (size_t)n * sizeof(float);       off = (off + 255) & ~(size_t)255;
    float* a2 = (float*)(ws + off);
    off += (size_t)n * sizeof(float);       off = (off + 255) & ~(size_t)255;
    int* deg = (int*)(ws + off);
    off += (size_t)n * sizeof(int);         off = (off + 255) & ~(size_t)255;
    int* ptr = (int*)(ws + off);
    off += (size_t)(n + 1) * sizeof(int);   off = (off + 255) & ~(size_t)255;
    int* rank = (int*)(ws + off);
    off += (size_t)e * sizeof(int);         off = (off + 255) & ~(size_t)255;
    uint2* sorted = (uint2*)(ws + off);

    hipMemsetAsync(deg, 0, (size_t)n * sizeof(int), stream);
    sniff_kernel<<<1, 64, 0, stream>>>((const u32*)x0, ei, flags);

    const int nchunk = (n + 31) / 32;       // 1563
    const int bpg = (nchunk + 3) / 4;       // blocks per matrix
    proj_kernel<true ><<<2 * bpg, 256, 0, stream>>>(x0, W1, b1, W2, b2, a1w, a1b,
                                                    a2w, a2b, xj, a1, a2, flags, n, nchunk, bpg);
    proj_kernel<false><<<2 * bpg, 256, 0, stream>>>(x0, W1, b1, W2, b2, a1w, a1b,
                                                    a2w, a2b, xj, a1, a2, flags, n, nchunk, bpg);

    int eblocks = (e + 255) / 256;
    hist_kernel<<<eblocks, 256, 0, stream>>>(ei, deg, rank, flags, e);
    int sblocks = (n + 1023) / 1024;
    scanA_kernel<<<sblocks, 256, 0, stream>>>(deg, ptr, bsum, n);
    scanB_kernel<<<1, 64, 0, stream>>>(bsum, ptr, sblocks, n);
    scanC_kernel<<<sblocks, 256, 0, stream>>>(ptr, bsum, n);
    scatter_kernel<<<eblocks, 256, 0, stream>>>(ei, a1, a2, ptr, rank, sorted, flags, e);

    int gblocks = (n + 3) / 4;
    gather_kernel<true ><<<gblocks, 256, 0, stream>>>(ptr, sorted, (const u32*)xj,
                                                      x0, d_out, flags, n);
    gather_kernel<false><<<gblocks, 256, 0, stream>>>(ptr, sorted, (const u32*)xj,
                                                      x0, d_out, flags, n);
}

// Round 5
// 215.404 us; speedup vs baseline: 1.2499x; 1.0677x over previous
//
#include <hip/hip_runtime.h>
#include <hip/hip_bf16.h>

typedef unsigned int u32;
typedef unsigned short u16;

#define DIM 128
#define LWS 136   // LDS row stride in u16 (128 + 8 pad = 272 B, 16B-aligned)

typedef __bf16 bfrag __attribute__((ext_vector_type(8)));   // MFMA A/B frag (4 VGPRs)
typedef float  facc  __attribute__((ext_vector_type(4)));   // MFMA C/D frag

__device__ __forceinline__ float2 bfpair(u32 u) {
    union { u32 i; float f; } lo, hi;
    lo.i = (u & 0xFFFFu) << 16;
    hi.i = u & 0xFFFF0000u;
    return make_float2(lo.f, hi.f);
}
__device__ __forceinline__ float bf1(u16 h) {
    union { u32 i; float f; } a; a.i = ((u32)h) << 16; return a.f;
}
__device__ __forceinline__ u16 f2bf(float f) {
    __hip_bfloat16 h = __float2bfloat16(f);   // RNE
    return *reinterpret_cast<u16*>(&h);
}
__device__ __forceinline__ u32 packbf(float x, float y) {
    return (u32)f2bf(x) | ((u32)f2bf(y) << 16);
}

template<bool BF16>
__device__ __forceinline__ float ldf(const void* p, int i) {
    if constexpr (BF16) return bf1(((const u16*)p)[i]);
    else                return ((const float*)p)[i];
}

// load an 8-element bf16 fragment from row-major [*,128] matrix (proven R2-R5)
template<bool BF16>
__device__ __forceinline__ bfrag ldfrag(const void* base, int row, int elt) {
    if constexpr (BF16) {
        const uint4* p = (const uint4*)((const u16*)base + (size_t)row * DIM + elt);
        return __builtin_bit_cast(bfrag, *p);
    } else {
        const float4* p = (const float4*)((const float*)base + (size_t)row * DIM + elt);
        float4 f0 = p[0], f1 = p[1];
        uint4 u = make_uint4(packbf(f0.x, f0.y), packbf(f0.z, f0.w),
                             packbf(f1.x, f1.y), packbf(f1.z, f1.w));
        return __builtin_bit_cast(bfrag, u);
    }
}

// ---------------------------------------------------------------------------
// Sniffer (R2-proven): flags[0]=1 if float tensors are bf16; flags[1]=1 if
// edge_index is int64 layout.
// ---------------------------------------------------------------------------
__global__ __launch_bounds__(64) void sniff_kernel(const u32* __restrict__ x0w,
                                                   const int* __restrict__ eiw,
                                                   int* __restrict__ flags) {
    int l = threadIdx.x;
    u32 w = x0w[l];
    u32 ef = (w >> 7) & 0xFF;                 // exponent of low halfword if bf16
    bool inr = (ef >= 99 && ef <= 141);
    unsigned long long m1 = __ballot(inr);
    bool zodd = (eiw[2 * l + 1] == 0);
    unsigned long long m2 = __ballot(zodd);
    if (l == 0) {
        flags[0] = (__popcll(m1) >= 48) ? 1 : 0;
        flags[1] = (__popcll(m2) >= 32) ? 1 : 0;
    }
}

// ---------------------------------------------------------------------------
// R9: fused proj + hist. The two are data-independent; hist is an atomic-
// throughput wall (800k atomicAdd-with-return, ~8/cycle device-wide, CUs
// idle) while proj is MFMA/LDS-bound (memory system idle). One grid,
// interleaved 1 proj block : (S-1) hist blocks so every CU hosts a mix and
// the atomic wait hides under MFMA.
//   grid = nbp * S blocks; b%S==0 -> proj block b/S; else hist block
//   (b/S)*(S-1) + b%S - 1 (bijective). Inner code of both parts unchanged
//   from the proven R8 kernels.
// ---------------------------------------------------------------------------
template<bool BF16>
__global__ __launch_bounds__(256) void proj_hist_kernel(
    const void* __restrict__ x0v,
    const void* __restrict__ W1v, const void* __restrict__ b1v,
    const void* __restrict__ W2v, const void* __restrict__ b2v,
    const void* __restrict__ a1wv, const void* __restrict__ a1bv,
    const void* __restrict__ a2wv, const void* __restrict__ a2bv,
    u16* __restrict__ xj, float* __restrict__ a1, float* __restrict__ a2,
    const int* __restrict__ ei, int* __restrict__ deg, int* __restrict__ rank,
    const int* __restrict__ flags, int n, int ne, int nchunk, int bpg, int S)
{
    if ((flags[0] != 0) != BF16) return;      // wrong dtype: ghost launch
    __shared__ u16 lw[128 * LWS];             // ~34 KB (hist blocks carry it too)

    const int b   = blockIdx.x;
    const int t   = threadIdx.x;
    const int nbp = 2 * bpg;

    if (b % S != 0) {
        // ---- hist part (R8-proven body, 1 edge/thread, max TLP) ----
        int hb = (b / S) * (S - 1) + (b % S) - 1;
        int i  = hb * 256 + t;
        if (i >= ne) return;
        int src = flags[1] ? ei[2 * i] : ei[i];
        rank[i] = atomicAdd(&deg[src], 1);
        return;
    }

    const int pid = b / S;                    // proj block id in [0, 2*bpg)
    if (pid >= nbp) return;
    const int grp = pid / bpg;                // 0: W1/a1, 1: W2/a2
    const int cb  = pid % bpg;

    const void* Wv  = grp ? W2v  : W1v;
    const void* bv  = grp ? b2v  : b1v;
    const void* awv = grp ? a2wv : a1wv;
    const void* abv = grp ? a2bv : a1bv;
    float* aout     = grp ? a2   : a1;

    // stage W -> LDS as bf16 (16B chunks, padded rows)
    for (int j = t; j < 2048; j += 256) {
        int r = j >> 4, c = j & 15;
        uint4 u;
        if constexpr (BF16) {
            u = *(const uint4*)((const u16*)Wv + (size_t)r * DIM + c * 8);
        } else {
            const float4* p = (const float4*)((const float*)Wv + (size_t)r * DIM + c * 8);
            float4 f0 = p[0], f1 = p[1];
            u = make_uint4(packbf(f0.x, f0.y), packbf(f0.z, f0.w),
                           packbf(f1.x, f1.y), packbf(f1.z, f1.w));
        }
        *(uint4*)(lw + (size_t)r * LWS + c * 8) = u;
    }
    __syncthreads();

    const int wid = t >> 6, l = t & 63;
    const int chunk = cb * 4 + wid;
    if (chunk >= nchunk) return;
    const int r0 = chunk * 32;
    const int lr = l & 15;                    // A row / B col within tile
    const int q  = l >> 4;                    // quad -> k slice, C row group

    // A fragments = x rows: 2 row-tiles x 4 k-slices (proven)
    bfrag a[2][4];
    #pragma unroll
    for (int rt = 0; rt < 2; ++rt) {
        int row = min(r0 + rt * 16 + lr, n - 1);  // clamp (stores guarded)
        #pragma unroll
        for (int k = 0; k < 4; ++k)
            a[rt][k] = ldfrag<BF16>(x0v, row, k * 32 + q * 8);
    }

    facc acc[2][8];
    #pragma unroll
    for (int rt = 0; rt < 2; ++rt)
        #pragma unroll
        for (int ct = 0; ct < 8; ++ct)
            acc[rt][ct] = (facc){0.f, 0.f, 0.f, 0.f};

    #pragma unroll
    for (int ct = 0; ct < 8; ++ct) {
        bfrag bb[4];
        const u16* lrow = lw + (size_t)(ct * 16 + lr) * LWS;
        #pragma unroll
        for (int k = 0; k < 4; ++k)
            bb[k] = *(const bfrag*)(lrow + k * 32 + q * 8);
        #pragma unroll
        for (int rt = 0; rt < 2; ++rt)
            #pragma unroll
            for (int k = 0; k < 4; ++k)
                acc[rt][ct] = __builtin_amdgcn_mfma_f32_16x16x32_bf16(
                    a[rt][k], bb[k], acc[rt][ct], 0, 0, 0);
    }

    // proven epilogue: bias + LeakyReLU; scalar xj stores; a-dot
    float s[2][4] = {{0.f,0.f,0.f,0.f},{0.f,0.f,0.f,0.f}};
    #pragma unroll
    for (int ct = 0; ct < 8; ++ct) {
        float bc  = ldf<BF16>(bv,  ct * 16 + lr);
        float awc = ldf<BF16>(awv, ct * 16 + lr);
        #pragma unroll
        for (int rt = 0; rt < 2; ++rt)
            #pragma unroll
            for (int reg = 0; reg < 4; ++reg) {
                float v = acc[rt][ct][reg] + bc;
                v = v >= 0.f ? v : 0.2f * v;          // LeakyReLU(0.2)
                int row = r0 + rt * 16 + q * 4 + reg;
                if (grp && row < n)
                    xj[(size_t)row * DIM + ct * 16 + lr] = f2bf(v);
                s[rt][reg] = fmaf(v, awc, s[rt][reg]);
            }
    }
    #pragma unroll
    for (int off = 1; off < 16; off <<= 1)
        #pragma unroll
        for (int rt = 0; rt < 2; ++rt)
            #pragma unroll
            for (int reg = 0; reg < 4; ++reg)
                s[rt][reg] += __shfl_xor(s[rt][reg], off);
    if (lr == 0) {
        float ab = ldf<BF16>(abv, 0);
        #pragma unroll
        for (int rt = 0; rt < 2; ++rt)
            #pragma unroll
            for (int reg = 0; reg < 4; ++reg) {
                int row = r0 + rt * 16 + q * 4 + reg;
                if (row < n) aout[row] = s[rt][reg] + ab;
            }
    }
}

// ---------------------------------------------------------------------------
// Parallel scan (3 phases, proven).
// ---------------------------------------------------------------------------
__global__ __launch_bounds__(256) void scanA_kernel(
    const int* __restrict__ deg, int* __restrict__ ptr,
    int* __restrict__ bsum, int n)
{
    __shared__ int wsums[4];
    const int t = threadIdx.x, lane = t & 63, w = t >> 6;
    const int i = blockIdx.x * 1024 + t * 4;

    int4 d = make_int4(0, 0, 0, 0);
    if (i < n) d = *(const int4*)(deg + i);      // n % 4 == 0
    int ts = d.x + d.y + d.z + d.w;
    int sc = ts;
    #pragma unroll
    for (int off = 1; off < 64; off <<= 1) {
        int v = __shfl_up(sc, off);
        if (lane >= off) sc += v;
    }
    if (lane == 63) wsums[w] = sc;
    __syncthreads();
    int wb = 0;
    #pragma unroll
    for (int j = 0; j < 4; ++j) if (j < w) wb += wsums[j];
    int excl = wb + sc - ts;
    if (i < n) {
        int4 o;
        o.x = excl; o.y = o.x + d.x; o.z = o.y + d.y; o.w = o.z + d.z;
        *(int4*)(ptr + i) = o;
    }
    if (t == 0) bsum[blockIdx.x] = wsums[0] + wsums[1] + wsums[2] + wsums[3];
}

__global__ __launch_bounds__(64) void scanB_kernel(
    int* __restrict__ bsum, int* __restrict__ ptr, int nblk, int n)
{
    int l = threadIdx.x;
    int v = (l < nblk) ? bsum[l] : 0;
    int s = v;
    #pragma unroll
    for (int off = 1; off < 64; off <<= 1) {
        int u = __shfl_up(s, off);
        if (l >= off) s += u;
    }
    if (l < nblk) bsum[l] = s - v;               // exclusive offsets
    if (l == 63) ptr[n] = s;                     // grand total == ne
}

__global__ __launch_bounds__(256) void scanC_kernel(
    int* __restrict__ ptr, const int* __restrict__ bsum, int n)
{
    const int i = blockIdx.x * 1024 + threadIdx.x * 4;
    if (i >= n) return;
    int off = bsum[blockIdx.x];
    int4 v = *(const int4*)(ptr + i);
    v.x += off; v.y += off; v.z += off; v.w += off;
    *(int4*)(ptr + i) = v;
}

// ---------------------------------------------------------------------------
// CSR step 3 (R8-proven): atomic-free scatter. pos = ptr[src] + rank[i].
// ---------------------------------------------------------------------------
__global__ __launch_bounds__(256) void scatter_kernel(
    const int* __restrict__ ei, const float* __restrict__ a1,
    const float* __restrict__ a2, const int* __restrict__ ptr,
    const int* __restrict__ rank, uint2* __restrict__ sorted,
    const int* __restrict__ flags, int ne)
{
    int i = blockIdx.x * 256 + threadIdx.x;
    if (i >= ne) return;
    int src, dst;
    if (flags[1]) { src = ei[2 * i]; dst = ei[2 * (ne + i)]; }
    else          { src = ei[i];     dst = ei[ne + i];       }
    int  r   = rank[i];
    int  pb  = ptr[src];
    float av  = a1[src] + a2[dst];
    float att = 1.0f / (1.0f + __expf(-av));
    uint2 rec; rec.x = (u32)dst; rec.y = __float_as_uint(att);
    sorted[pb + r] = rec;
}

// ---------------------------------------------------------------------------
// Gather (R6-proven): one wave per src node, lane l = cols 2l,2l+1.
// Depth-8 software pipeline; dual accumulators.
// ---------------------------------------------------------------------------
template<bool BF16>
__global__ __launch_bounds__(256) void gather_kernel(
    const int* __restrict__ ptr, const uint2* __restrict__ sorted,
    const u32* __restrict__ xjw, const void* __restrict__ x0v,
    void* __restrict__ outv, const int* __restrict__ flags, int n)
{
    if ((flags[0] != 0) != BF16) return;
    int s = blockIdx.x * 4 + (threadIdx.x >> 6);
    int l = threadIdx.x & 63;
    if (s >= n) return;

    float2 acc0, acc1;
    if constexpr (BF16) acc0 = bfpair(((const u32*)x0v)[(size_t)s * 64 + l]);
    else                acc0 = ((const float2*)x0v)[(size_t)s * 64 + l];
    acc1 = make_float2(0.f, 0.f);

    int k = ptr[s], end = ptr[s + 1];

    // main chunks: 8 edges in flight
    while (k + 8 <= end) {
        uint2 r[8];
        #pragma unroll
        for (int j = 0; j < 8; ++j) r[j] = sorted[k + j];
        u32 w[8];
        #pragma unroll
        for (int j = 0; j < 8; ++j) w[j] = xjw[(size_t)r[j].x * 64 + l];
        #pragma unroll
        for (int j = 0; j < 8; ++j) {
            float att = __uint_as_float(r[j].y);
            float2 xv = bfpair(w[j]);
            if (j & 1) { acc1.x = fmaf(att, xv.x, acc1.x);
                         acc1.y = fmaf(att, xv.y, acc1.y); }
            else       { acc0.x = fmaf(att, xv.x, acc0.x);
                         acc0.y = fmaf(att, xv.y, acc0.y); }
        }
        k += 8;
    }
    // one chunk of 4
    if (k + 4 <= end) {
        uint2 r[4];
        #pragma unroll
        for (int j = 0; j < 4; ++j) r[j] = sorted[k + j];
        u32 w[4];
        #pragma unroll
        for (int j = 0; j < 4; ++j) w[j] = xjw[(size_t)r[j].x * 64 + l];
        #pragma unroll
        for (int j = 0; j < 4; ++j) {
            float att = __uint_as_float(r[j].y);
            float2 xv = bfpair(w[j]);
            if (j & 1) { acc1.x = fmaf(att, xv.x, acc1.x);
                         acc1.y = fmaf(att, xv.y, acc1.y); }
            else       { acc0.x = fmaf(att, xv.x, acc0.x);
                         acc0.y = fmaf(att, xv.y, acc0.y); }
        }
        k += 4;
    }
    // scalar tail (<=3)
    for (; k < end; ++k) {
        uint2 cur = sorted[k];
        float att = __uint_as_float(cur.y);
        float2 xv = bfpair(xjw[(size_t)cur.x * 64 + l]);
        acc0.x = fmaf(att, xv.x, acc0.x);
        acc0.y = fmaf(att, xv.y, acc0.y);
    }
    acc0.x += acc1.x;
    acc0.y += acc1.y;

    if constexpr (BF16) ((u32*)outv)[(size_t)s * 64 + l] = packbf(acc0.x, acc0.y);
    else                ((float2*)outv)[(size_t)s * 64 + l] = acc0;
}

extern "C" void kernel_launch(void* const* d_in, const int* in_sizes, int n_in,
                              void* d_out, int out_size, void* d_ws, size_t ws_size,
                              hipStream_t stream)
{
    const void* x0  = d_in[0];
    /* d_in[1] = x1: unused by the reference computation */
    const int*  ei  = (const int*)d_in[2];
    const void* W1  = d_in[3];
    const void* b1  = d_in[4];
    const void* W2  = d_in[5];
    const void* b2  = d_in[6];
    const void* a1w = d_in[7];
    const void* a1b = d_in[8];
    const void* a2w = d_in[9];
    const void* a2b = d_in[10];

    const int n = in_sizes[0] / DIM;        // 50000
    const int e = in_sizes[2] / 2;          // 800000

    // ws: flags | bsum | xj bf16 | a1 | a2 | deg | ptr | rank | sorted(uint2)
    char* ws = (char*)d_ws;
    int* flags = (int*)ws;
    int* bsum  = (int*)(ws + 256);          // up to 192 block sums
    size_t off = 1024;
    u16* xj = (u16*)(ws + off);
    off += (size_t)n * DIM * sizeof(u16);   off = (off + 255) & ~(size_t)255;
    float* a1 = (float*)(ws + off);
    off += (size_t)n * sizeof(float);       off = (off + 255) & ~(size_t)255;
    float* a2 = (float*)(ws + off);
    off += (size_t)n * sizeof(float);       off = (off + 255) & ~(size_t)255;
    int* deg = (int*)(ws + off);
    off += (size_t)n * sizeof(int);         off = (off + 255) & ~(size_t)255;
    int* ptr = (int*)(ws + off);
    off += (size_t)(n + 1) * sizeof(int);   off = (off + 255) & ~(size_t)255;
    int* rank = (int*)(ws + off);
    off += (size_t)e * sizeof(int);         off = (off + 255) & ~(size_t)255;
    uint2* sorted = (uint2*)(ws + off);

    hipMemsetAsync(deg, 0, (size_t)n * sizeof(int), stream);
    sniff_kernel<<<1, 64, 0, stream>>>((const u32*)x0, ei, flags);

    const int nchunk = (n + 31) / 32;       // 1563
    const int bpg = (nchunk + 3) / 4;       // blocks per matrix
    const int nbp = 2 * bpg;                // proj blocks (782)
    const int eblocks = (e + 255) / 256;    // hist/scatter blocks (3125)
    // interleave 1 proj : (S-1) hist so every CU hosts a mix
    const int S = 1 + (eblocks + nbp - 1) / nbp;   // 5
    const int fgrid = nbp * S;                     // 3910 (covers both parts)

    proj_hist_kernel<true ><<<fgrid, 256, 0, stream>>>(x0, W1, b1, W2, b2,
        a1w, a1b, a2w, a2b, xj, a1, a2, ei, deg, rank, flags, n, e, nchunk, bpg, S);
    proj_hist_kernel<false><<<fgrid, 256, 0, stream>>>(x0, W1, b1, W2, b2,
        a1w, a1b, a2w, a2b, xj, a1, a2, ei, deg, rank, flags, n, e, nchunk, bpg, S);

    int sblocks = (n + 1023) / 1024;
    scanA_kernel<<<sblocks, 256, 0, stream>>>(deg, ptr, bsum, n);
    scanB_kernel<<<1, 64, 0, stream>>>(bsum, ptr, sblocks, n);
    scanC_kernel<<<sblocks, 256, 0, stream>>>(ptr, bsum, n);
    scatter_kernel<<<eblocks, 256, 0, stream>>>(ei, a1, a2, ptr, rank, sorted, flags, e);

    int gblocks = (n + 3) / 4;
    gather_kernel<true ><<<gblocks, 256, 0, stream>>>(ptr, sorted, (const u32*)xj,
                                                      x0, d_out, flags, n);
    gather_kernel<false><<<gblocks, 256, 0, stream>>>(ptr, sorted, (const u32*)xj,
                                                      x0, d_out, flags, n);
}

// Round 6
// 214.676 us; speedup vs baseline: 1.2541x; 1.0034x over previous
//
#include <hip/hip_runtime.h>
#include <hip/hip_bf16.h>

typedef unsigned int u32;
typedef unsigned short u16;

#define DIM 128
#define LWS 136   // LDS row stride in u16 (128 + 8 pad = 272 B, 16B-aligned)
#define DEGPAD 4  // deg[src << DEGPAD]: one counter per 64B line (R10)

typedef __bf16 bfrag __attribute__((ext_vector_type(8)));   // MFMA A/B frag (4 VGPRs)
typedef float  facc  __attribute__((ext_vector_type(4)));   // MFMA C/D frag

__device__ __forceinline__ float2 bfpair(u32 u) {
    union { u32 i; float f; } lo, hi;
    lo.i = (u & 0xFFFFu) << 16;
    hi.i = u & 0xFFFF0000u;
    return make_float2(lo.f, hi.f);
}
__device__ __forceinline__ float bf1(u16 h) {
    union { u32 i; float f; } a; a.i = ((u32)h) << 16; return a.f;
}
__device__ __forceinline__ u16 f2bf(float f) {
    __hip_bfloat16 h = __float2bfloat16(f);   // RNE
    return *reinterpret_cast<u16*>(&h);
}
__device__ __forceinline__ u32 packbf(float x, float y) {
    return (u32)f2bf(x) | ((u32)f2bf(y) << 16);
}

template<bool BF16>
__device__ __forceinline__ float ldf(const void* p, int i) {
    if constexpr (BF16) return bf1(((const u16*)p)[i]);
    else                return ((const float*)p)[i];
}

// load an 8-element bf16 fragment from row-major [*,128] matrix (proven R2-R5)
template<bool BF16>
__device__ __forceinline__ bfrag ldfrag(const void* base, int row, int elt) {
    if constexpr (BF16) {
        const uint4* p = (const uint4*)((const u16*)base + (size_t)row * DIM + elt);
        return __builtin_bit_cast(bfrag, *p);
    } else {
        const float4* p = (const float4*)((const float*)base + (size_t)row * DIM + elt);
        float4 f0 = p[0], f1 = p[1];
        uint4 u = make_uint4(packbf(f0.x, f0.y), packbf(f0.z, f0.w),
                             packbf(f1.x, f1.y), packbf(f1.z, f1.w));
        return __builtin_bit_cast(bfrag, u);
    }
}

// ---------------------------------------------------------------------------
// Sniffer (R2-proven): flags[0]=1 if float tensors are bf16; flags[1]=1 if
// edge_index is int64 layout.
// ---------------------------------------------------------------------------
__global__ __launch_bounds__(64) void sniff_kernel(const u32* __restrict__ x0w,
                                                   const int* __restrict__ eiw,
                                                   int* __restrict__ flags) {
    int l = threadIdx.x;
    u32 w = x0w[l];
    u32 ef = (w >> 7) & 0xFF;                 // exponent of low halfword if bf16
    bool inr = (ef >= 99 && ef <= 141);
    unsigned long long m1 = __ballot(inr);
    bool zodd = (eiw[2 * l + 1] == 0);
    unsigned long long m2 = __ballot(zodd);
    if (l == 0) {
        flags[0] = (__popcll(m1) >= 48) ? 1 : 0;
        flags[1] = (__popcll(m2) >= 32) ? 1 : 0;
    }
}

// ---------------------------------------------------------------------------
// R9-proven fused proj + hist (1 proj : S-1 hist interleave).
// R10: deg is line-padded (deg[src<<4]) — R8/R9 profile showed hist's 42us
// was cache-line ping-pong: 16 counters/line x 16 edges = 256 device-scope
// atomics serializing per-line acquisition (WRITE_SIZE 28MB for a 200KB
// array = 140x write-back amplification). One counter per 64B line cuts the
// per-line serial chain 16x. Rank semantics unchanged.
// ---------------------------------------------------------------------------
template<bool BF16>
__global__ __launch_bounds__(256) void proj_hist_kernel(
    const void* __restrict__ x0v,
    const void* __restrict__ W1v, const void* __restrict__ b1v,
    const void* __restrict__ W2v, const void* __restrict__ b2v,
    const void* __restrict__ a1wv, const void* __restrict__ a1bv,
    const void* __restrict__ a2wv, const void* __restrict__ a2bv,
    u16* __restrict__ xj, float* __restrict__ a1, float* __restrict__ a2,
    const int* __restrict__ ei, int* __restrict__ deg, int* __restrict__ rank,
    const int* __restrict__ flags, int n, int ne, int nchunk, int bpg, int S)
{
    if ((flags[0] != 0) != BF16) return;      // wrong dtype: ghost launch
    __shared__ u16 lw[128 * LWS];             // ~34 KB (hist blocks carry it too)

    const int b   = blockIdx.x;
    const int t   = threadIdx.x;
    const int nbp = 2 * bpg;

    if (b % S != 0) {
        // ---- hist part (1 edge/thread, max TLP; padded deg) ----
        int hb = (b / S) * (S - 1) + (b % S) - 1;
        int i  = hb * 256 + t;
        if (i >= ne) return;
        int src = flags[1] ? ei[2 * i] : ei[i];
        rank[i] = atomicAdd(&deg[src << DEGPAD], 1);
        return;
    }

    const int pid = b / S;                    // proj block id in [0, 2*bpg)
    if (pid >= nbp) return;
    const int grp = pid / bpg;                // 0: W1/a1, 1: W2/a2
    const int cb  = pid % bpg;

    const void* Wv  = grp ? W2v  : W1v;
    const void* bv  = grp ? b2v  : b1v;
    const void* awv = grp ? a2wv : a1wv;
    const void* abv = grp ? a2bv : a1bv;
    float* aout     = grp ? a2   : a1;

    // stage W -> LDS as bf16 (16B chunks, padded rows)
    for (int j = t; j < 2048; j += 256) {
        int r = j >> 4, c = j & 15;
        uint4 u;
        if constexpr (BF16) {
            u = *(const uint4*)((const u16*)Wv + (size_t)r * DIM + c * 8);
        } else {
            const float4* p = (const float4*)((const float*)Wv + (size_t)r * DIM + c * 8);
            float4 f0 = p[0], f1 = p[1];
            u = make_uint4(packbf(f0.x, f0.y), packbf(f0.z, f0.w),
                           packbf(f1.x, f1.y), packbf(f1.z, f1.w));
        }
        *(uint4*)(lw + (size_t)r * LWS + c * 8) = u;
    }
    __syncthreads();

    const int wid = t >> 6, l = t & 63;
    const int chunk = cb * 4 + wid;
    if (chunk >= nchunk) return;
    const int r0 = chunk * 32;
    const int lr = l & 15;                    // A row / B col within tile
    const int q  = l >> 4;                    // quad -> k slice, C row group

    // A fragments = x rows: 2 row-tiles x 4 k-slices (proven)
    bfrag a[2][4];
    #pragma unroll
    for (int rt = 0; rt < 2; ++rt) {
        int row = min(r0 + rt * 16 + lr, n - 1);  // clamp (stores guarded)
        #pragma unroll
        for (int k = 0; k < 4; ++k)
            a[rt][k] = ldfrag<BF16>(x0v, row, k * 32 + q * 8);
    }

    facc acc[2][8];
    #pragma unroll
    for (int rt = 0; rt < 2; ++rt)
        #pragma unroll
        for (int ct = 0; ct < 8; ++ct)
            acc[rt][ct] = (facc){0.f, 0.f, 0.f, 0.f};

    #pragma unroll
    for (int ct = 0; ct < 8; ++ct) {
        bfrag bb[4];
        const u16* lrow = lw + (size_t)(ct * 16 + lr) * LWS;
        #pragma unroll
        for (int k = 0; k < 4; ++k)
            bb[k] = *(const bfrag*)(lrow + k * 32 + q * 8);
        #pragma unroll
        for (int rt = 0; rt < 2; ++rt)
            #pragma unroll
            for (int k = 0; k < 4; ++k)
                acc[rt][ct] = __builtin_amdgcn_mfma_f32_16x16x32_bf16(
                    a[rt][k], bb[k], acc[rt][ct], 0, 0, 0);
    }

    // proven epilogue: bias + LeakyReLU; scalar xj stores; a-dot
    float s[2][4] = {{0.f,0.f,0.f,0.f},{0.f,0.f,0.f,0.f}};
    #pragma unroll
    for (int ct = 0; ct < 8; ++ct) {
        float bc  = ldf<BF16>(bv,  ct * 16 + lr);
        float awc = ldf<BF16>(awv, ct * 16 + lr);
        #pragma unroll
        for (int rt = 0; rt < 2; ++rt)
            #pragma unroll
            for (int reg = 0; reg < 4; ++reg) {
                float v = acc[rt][ct][reg] + bc;
                v = v >= 0.f ? v : 0.2f * v;          // LeakyReLU(0.2)
                int row = r0 + rt * 16 + q * 4 + reg;
                if (grp && row < n)
                    xj[(size_t)row * DIM + ct * 16 + lr] = f2bf(v);
                s[rt][reg] = fmaf(v, awc, s[rt][reg]);
            }
    }
    #pragma unroll
    for (int off = 1; off < 16; off <<= 1)
        #pragma unroll
        for (int rt = 0; rt < 2; ++rt)
            #pragma unroll
            for (int reg = 0; reg < 4; ++reg)
                s[rt][reg] += __shfl_xor(s[rt][reg], off);
    if (lr == 0) {
        float ab = ldf<BF16>(abv, 0);
        #pragma unroll
        for (int rt = 0; rt < 2; ++rt)
            #pragma unroll
            for (int reg = 0; reg < 4; ++reg) {
                int row = r0 + rt * 16 + q * 4 + reg;
                if (row < n) aout[row] = s[rt][reg] + ab;
            }
    }
}

// ---------------------------------------------------------------------------
// Parallel scan (3 phases, proven). R10: deg reads are line-strided.
// ---------------------------------------------------------------------------
__global__ __launch_bounds__(256) void scanA_kernel(
    const int* __restrict__ deg, int* __restrict__ ptr,
    int* __restrict__ bsum, int n)
{
    __shared__ int wsums[4];
    const int t = threadIdx.x, lane = t & 63, w = t >> 6;
    const int i = blockIdx.x * 1024 + t * 4;

    int4 d = make_int4(0, 0, 0, 0);
    if (i < n) {                                  // n % 4 == 0
        d.x = deg[(size_t)(i + 0) << DEGPAD];
        d.y = deg[(size_t)(i + 1) << DEGPAD];
        d.z = deg[(size_t)(i + 2) << DEGPAD];
        d.w = deg[(size_t)(i + 3) << DEGPAD];
    }
    int ts = d.x + d.y + d.z + d.w;
    int sc = ts;
    #pragma unroll
    for (int off = 1; off < 64; off <<= 1) {
        int v = __shfl_up(sc, off);
        if (lane >= off) sc += v;
    }
    if (lane == 63) wsums[w] = sc;
    __syncthreads();
    int wb = 0;
    #pragma unroll
    for (int j = 0; j < 4; ++j) if (j < w) wb += wsums[j];
    int excl = wb + sc - ts;
    if (i < n) {
        int4 o;
        o.x = excl; o.y = o.x + d.x; o.z = o.y + d.y; o.w = o.z + d.z;
        *(int4*)(ptr + i) = o;
    }
    if (t == 0) bsum[blockIdx.x] = wsums[0] + wsums[1] + wsums[2] + wsums[3];
}

__global__ __launch_bounds__(64) void scanB_kernel(
    int* __restrict__ bsum, int* __restrict__ ptr, int nblk, int n)
{
    int l = threadIdx.x;
    int v = (l < nblk) ? bsum[l] : 0;
    int s = v;
    #pragma unroll
    for (int off = 1; off < 64; off <<= 1) {
        int u = __shfl_up(s, off);
        if (l >= off) s += u;
    }
    if (l < nblk) bsum[l] = s - v;               // exclusive offsets
    if (l == 63) ptr[n] = s;                     // grand total == ne
}

__global__ __launch_bounds__(256) void scanC_kernel(
    int* __restrict__ ptr, const int* __restrict__ bsum, int n)
{
    const int i = blockIdx.x * 1024 + threadIdx.x * 4;
    if (i >= n) return;
    int off = bsum[blockIdx.x];
    int4 v = *(const int4*)(ptr + i);
    v.x += off; v.y += off; v.z += off; v.w += off;
    *(int4*)(ptr + i) = v;
}

// ---------------------------------------------------------------------------
// CSR step 3 (R8-proven): atomic-free scatter. pos = ptr[src] + rank[i].
// ---------------------------------------------------------------------------
__global__ __launch_bounds__(256) void scatter_kernel(
    const int* __restrict__ ei, const float* __restrict__ a1,
    const float* __restrict__ a2, const int* __restrict__ ptr,
    const int* __restrict__ rank, uint2* __restrict__ sorted,
    const int* __restrict__ flags, int ne)
{
    int i = blockIdx.x * 256 + threadIdx.x;
    if (i >= ne) return;
    int src, dst;
    if (flags[1]) { src = ei[2 * i]; dst = ei[2 * (ne + i)]; }
    else          { src = ei[i];     dst = ei[ne + i];       }
    int  r   = rank[i];
    int  pb  = ptr[src];
    float av  = a1[src] + a2[dst];
    float att = 1.0f / (1.0f + __expf(-av));
    uint2 rec; rec.x = (u32)dst; rec.y = __float_as_uint(att);
    sorted[pb + r] = rec;
}

// ---------------------------------------------------------------------------
// Gather (R6-proven): one wave per src node, lane l = cols 2l,2l+1.
// Depth-8 software pipeline; dual accumulators.
// ---------------------------------------------------------------------------
template<bool BF16>
__global__ __launch_bounds__(256) void gather_kernel(
    const int* __restrict__ ptr, const uint2* __restrict__ sorted,
    const u32* __restrict__ xjw, const void* __restrict__ x0v,
    void* __restrict__ outv, const int* __restrict__ flags, int n)
{
    if ((flags[0] != 0) != BF16) return;
    int s = blockIdx.x * 4 + (threadIdx.x >> 6);
    int l = threadIdx.x & 63;
    if (s >= n) return;

    float2 acc0, acc1;
    if constexpr (BF16) acc0 = bfpair(((const u32*)x0v)[(size_t)s * 64 + l]);
    else                acc0 = ((const float2*)x0v)[(size_t)s * 64 + l];
    acc1 = make_float2(0.f, 0.f);

    int k = ptr[s], end = ptr[s + 1];

    // main chunks: 8 edges in flight
    while (k + 8 <= end) {
        uint2 r[8];
        #pragma unroll
        for (int j = 0; j < 8; ++j) r[j] = sorted[k + j];
        u32 w[8];
        #pragma unroll
        for (int j = 0; j < 8; ++j) w[j] = xjw[(size_t)r[j].x * 64 + l];
        #pragma unroll
        for (int j = 0; j < 8; ++j) {
            float att = __uint_as_float(r[j].y);
            float2 xv = bfpair(w[j]);
            if (j & 1) { acc1.x = fmaf(att, xv.x, acc1.x);
                         acc1.y = fmaf(att, xv.y, acc1.y); }
            else       { acc0.x = fmaf(att, xv.x, acc0.x);
                         acc0.y = fmaf(att, xv.y, acc0.y); }
        }
        k += 8;
    }
    // one chunk of 4
    if (k + 4 <= end) {
        uint2 r[4];
        #pragma unroll
        for (int j = 0; j < 4; ++j) r[j] = sorted[k + j];
        u32 w[4];
        #pragma unroll
        for (int j = 0; j < 4; ++j) w[j] = xjw[(size_t)r[j].x * 64 + l];
        #pragma unroll
        for (int j = 0; j < 4; ++j) {
            float att = __uint_as_float(r[j].y);
            float2 xv = bfpair(w[j]);
            if (j & 1) { acc1.x = fmaf(att, xv.x, acc1.x);
                         acc1.y = fmaf(att, xv.y, acc1.y); }
            else       { acc0.x = fmaf(att, xv.x, acc0.x);
                         acc0.y = fmaf(att, xv.y, acc0.y); }
        }
        k += 4;
    }
    // scalar tail (<=3)
    for (; k < end; ++k) {
        uint2 cur = sorted[k];
        float att = __uint_as_float(cur.y);
        float2 xv = bfpair(xjw[(size_t)cur.x * 64 + l]);
        acc0.x = fmaf(att, xv.x, acc0.x);
        acc0.y = fmaf(att, xv.y, acc0.y);
    }
    acc0.x += acc1.x;
    acc0.y += acc1.y;

    if constexpr (BF16) ((u32*)outv)[(size_t)s * 64 + l] = packbf(acc0.x, acc0.y);
    else                ((float2*)outv)[(size_t)s * 64 + l] = acc0;
}

extern "C" void kernel_launch(void* const* d_in, const int* in_sizes, int n_in,
                              void* d_out, int out_size, void* d_ws, size_t ws_size,
                              hipStream_t stream)
{
    const void* x0  = d_in[0];
    /* d_in[1] = x1: unused by the reference computation */
    const int*  ei  = (const int*)d_in[2];
    const void* W1  = d_in[3];
    const void* b1  = d_in[4];
    const void* W2  = d_in[5];
    const void* b2  = d_in[6];
    const void* a1w = d_in[7];
    const void* a1b = d_in[8];
    const void* a2w = d_in[9];
    const void* a2b = d_in[10];

    const int n = in_sizes[0] / DIM;        // 50000
    const int e = in_sizes[2] / 2;          // 800000

    // ws: flags | bsum | xj bf16 | a1 | a2 | deg(padded) | ptr | rank | sorted
    char* ws = (char*)d_ws;
    int* flags = (int*)ws;
    int* bsum  = (int*)(ws + 256);          // up to 192 block sums
    size_t off = 1024;
    u16* xj = (u16*)(ws + off);
    off += (size_t)n * DIM * sizeof(u16);   off = (off + 255) & ~(size_t)255;
    float* a1 = (float*)(ws + off);
    off += (size_t)n * sizeof(float);       off = (off + 255) & ~(size_t)255;
    float* a2 = (float*)(ws + off);
    off += (size_t)n * sizeof(float);       off = (off + 255) & ~(size_t)255;
    int* deg = (int*)(ws + off);
    off += ((size_t)n << DEGPAD) * sizeof(int); off = (off + 255) & ~(size_t)255;
    int* ptr = (int*)(ws + off);
    off += (size_t)(n + 1) * sizeof(int);   off = (off + 255) & ~(size_t)255;
    int* rank = (int*)(ws + off);
    off += (size_t)e * sizeof(int);         off = (off + 255) & ~(size_t)255;
    uint2* sorted = (uint2*)(ws + off);

    hipMemsetAsync(deg, 0, ((size_t)n << DEGPAD) * sizeof(int), stream);
    sniff_kernel<<<1, 64, 0, stream>>>((const u32*)x0, ei, flags);

    const int nchunk = (n + 31) / 32;       // 1563
    const int bpg = (nchunk + 3) / 4;       // blocks per matrix
    const int nbp = 2 * bpg;                // proj blocks (782)
    const int eblocks = (e + 255) / 256;    // hist/scatter blocks (3125)
    // interleave 1 proj : (S-1) hist so every CU hosts a mix
    const int S = 1 + (eblocks + nbp - 1) / nbp;   // 5
    const int fgrid = nbp * S;                     // 3910 (covers both parts)

    proj_hist_kernel<true ><<<fgrid, 256, 0, stream>>>(x0, W1, b1, W2, b2,
        a1w, a1b, a2w, a2b, xj, a1, a2, ei, deg, rank, flags, n, e, nchunk, bpg, S);
    proj_hist_kernel<false><<<fgrid, 256, 0, stream>>>(x0, W1, b1, W2, b2,
        a1w, a1b, a2w, a2b, xj, a1, a2, ei, deg, rank, flags, n, e, nchunk, bpg, S);

    int sblocks = (n + 1023) / 1024;
    scanA_kernel<<<sblocks, 256, 0, stream>>>(deg, ptr, bsum, n);
    scanB_kernel<<<1, 64, 0, stream>>>(bsum, ptr, sblocks, n);
    scanC_kernel<<<sblocks, 256, 0, stream>>>(ptr, bsum, n);
    scatter_kernel<<<eblocks, 256, 0, stream>>>(ei, a1, a2, ptr, rank, sorted, flags, e);

    int gblocks = (n + 3) / 4;
    gather_kernel<true ><<<gblocks, 256, 0, stream>>>(ptr, sorted, (const u32*)xj,
                                                      x0, d_out, flags, n);
    gather_kernel<false><<<gblocks, 256, 0, stream>>>(ptr, sorted, (const u32*)xj,
                                                      x0, d_out, flags, n);
}